// Round 9
// baseline (544.959 us; speedup 1.0000x reference)
//
#include <hip/hip_runtime.h>

#define NN   100000
#define EE   3200000
#define DIN  83
#define DHID 1024
#define NCLS 25
#define XPAD 96    // x/ax bf16 row padding (192 B = 3 cache lines)
#define ZPAD 32    // z bf16 row padding (64 B = 1 cache line)

#define NBK     391   // buckets of 256 rows (row >> 8)
#define SLAB    10240 // slab entries per bucket (mean 8192, sigma 90 -> 22 sigma)
#define CHUNK   8192  // edges per partition block

typedef __attribute__((__ext_vector_type__(8))) short sh8;
typedef __attribute__((__ext_vector_type__(4))) float f4_t;

static __device__ __forceinline__ float relu_(float v) { return v > 0.f ? v : 0.f; }

// f32 -> bf16 (RNE)
static __device__ __forceinline__ unsigned short f2bf(float f) {
  unsigned int u = __float_as_uint(f);
  unsigned int r = u + 0x7FFFu + ((u >> 16) & 1u);
  return (unsigned short)(r >> 16);
}
// packed bf16 pair -> two f32
static __device__ __forceinline__ float bflo(unsigned int q) {
  return __uint_as_float(q << 16);
}
static __device__ __forceinline__ float bfhi(unsigned int q) {
  return __uint_as_float(q & 0xFFFF0000u);
}

// K1 (merged prelude): conv1d+sum+relu -> x (LDS-staged, coalesced);
// w1t/w2t transposes ; gcur zero ; counts zero.
// Block = 16 nodes: stage 16x83 floats coalesced into LDS, 192 threads compute.
__global__ __launch_bounds__(256) void prelude_k(
    const float* __restrict__ feature, const float* __restrict__ conv_w,
    const float* __restrict__ conv_b, unsigned short* __restrict__ x,
    const float* __restrict__ W1, unsigned short* __restrict__ w1t,
    const float* __restrict__ W2, unsigned short* __restrict__ w2t,
    int* __restrict__ gcur, int* __restrict__ counts) {
  const int tid = threadIdx.x;
  int t = blockIdx.x * 256 + tid;
  // --- aux ranges (low global ids) ---
  if (t < DHID * XPAD) {              // w1t[1024][96] -> [96][1024], K zero-pad
    int k = t / DHID;
    int n = t - k * DHID;
    float v = (k < DIN) ? W1[k * DHID + n] : 0.f;
    w1t[n * XPAD + k] = f2bf(v);
  }
  if (t < 32 * DHID) {                // w2t[32][1024], N zero-padded
    int k = t / 32;
    int n = t - k * 32;
    float v = (n < NCLS) ? W2[k * NCLS + n] : 0.f;
    w2t[n * DHID + k] = f2bf(v);
  }
  if (t < NBK * 16) gcur[t] = 0;
  if (t < NN) counts[t] = 0;
  // --- conv: 16 nodes per block ---
  const int nb0 = blockIdx.x * 16;
  if (nb0 >= NN) return;
  __shared__ float fs[16 * 84];       // 83 floats/node, pad to 84
  const size_t base = (size_t)nb0 * DIN;
  for (int i = tid; i < 16 * DIN; i += 256) {
    int nl = i / DIN;
    int dd = i - nl * DIN;
    fs[nl * 84 + dd] = feature[base + i];
  }
  __syncthreads();
  if (tid >= 192) return;             // 16 nodes x 12 groups
  int nl = tid / 12;
  int g = tid - nl * 12;
  int i0 = g * 8;
  float ws0 = conv_w[0] + conv_w[5] + conv_w[10] + conv_w[15];
  float ws1 = conv_w[1] + conv_w[6] + conv_w[11] + conv_w[16];
  float ws2 = conv_w[2] + conv_w[7] + conv_w[12] + conv_w[17];
  float ws3 = conv_w[3] + conv_w[8] + conv_w[13] + conv_w[18];
  float ws4 = conv_w[4] + conv_w[9] + conv_w[14] + conv_w[19];
  float bs  = conv_b[0] + conv_b[1] + conv_b[2] + conv_b[3];
  const float* f = &fs[nl * 84];
  float fv[12];
#pragma unroll
  for (int k = 0; k < 12; ++k) {
    int idx = i0 - 2 + k;
    fv[k] = (idx >= 0 && idx < DIN) ? f[idx] : 0.f;
  }
  sh8 vout;
#pragma unroll
  for (int j = 0; j < 8; ++j) {
    int i = i0 + j;
    unsigned short o = 0;
    if (i < DIN) {
      float acc = bs + ws0 * fv[j] + ws1 * fv[j + 1] + ws2 * fv[j + 2] +
                  ws3 * fv[j + 3] + ws4 * fv[j + 4];
      o = f2bf(relu_(acc));
    }
    vout[j] = (short)o;
  }
  *(sh8*)&x[(size_t)(nb0 + nl) * XPAD + i0] = vout;
}

// Pass 1: partition into per-bucket SLABS via direct atomic reservation,
// PLUS global per-row histogram (replaces fine_scatter's Phase A).
__global__ __launch_bounds__(256) void partition_k(
    const float* __restrict__ vals, const int* __restrict__ row,
    const int* __restrict__ col, int* __restrict__ gcur,
    int2* __restrict__ tmp, int* __restrict__ counts) {
  __shared__ int cnt[NBK];
  __shared__ int lcur[NBK];
  const int tid = threadIdx.x;
  const int cb = blockIdx.x * CHUNK;
  const int csize = (cb + CHUNK <= EE) ? CHUNK : (EE - cb);

  for (int b = tid; b < NBK; b += 256) cnt[b] = 0;
  __syncthreads();
  for (int i = tid; i < csize; i += 256) {
    int r = row[cb + i];
    atomicAdd(&cnt[r >> 8], 1);
    atomicAdd(&counts[r], 1);         // global per-row hist (L2-resident 400KB)
  }
  __syncthreads();
  for (int b = tid; b < NBK; b += 256)
    lcur[b] = cnt[b] ? (b * SLAB + atomicAdd(&gcur[b * 16], cnt[b])) : 0;
  __syncthreads();
  for (int i = tid; i < csize; i += 256) {
    int r = row[cb + i];
    int pos = atomicAdd(&lcur[r >> 8], 1);
    tmp[pos] = make_int2(col[cb + i] | ((r & 255) << 17),
                         __float_as_int(vals[cb + i]));
  }
}

// Pass 2: per-bucket scan (from global counts) + scatter. No histogram pass:
// tmp is read exactly once. csr stays slab-addressed (offs absolute).
__global__ __launch_bounds__(512) void fine_scatter2_k(
    const int* __restrict__ gcur, const int* __restrict__ counts,
    const int2* __restrict__ tmp, int2* __restrict__ csr,
    int* __restrict__ offs) {
  __shared__ int sd[256];
  __shared__ int lcur[256];
  const int tid = threadIdx.x;
  const int b = blockIdx.x;
  const int r0 = b * 256;
  const int gstart = b * SLAB;
  const int nedge = gcur[b * 16];
  // Phase B: exclusive scan of 256 row counts (first 256 threads)
  int v = 0;
  if (tid < 256) {
    int r = r0 + tid;
    v = (r < NN) ? counts[r] : 0;
    sd[tid] = v;
  }
  __syncthreads();
  for (int off = 1; off < 256; off <<= 1) {
    int add = (tid >= off && tid < 256) ? sd[tid - off] : 0;
    __syncthreads();
    if (tid < 256) sd[tid] += add;
    __syncthreads();
  }
  if (tid < 256) {
    int excl = gstart + sd[tid] - v;
    int r = r0 + tid;
    if (r < NN) offs[r] = excl;
    lcur[tid] = excl;
  }
  __syncthreads();
  // Phase C: scatter within the bucket's slab window (L2-local)
  for (int i = tid; i < nedge; i += 512) {
    int2 p = tmp[gstart + i];
    int rl = ((unsigned)p.x) >> 17;
    int pos = atomicAdd(&lcur[rl], 1);
    csr[pos] = make_int2(p.x & 0x1FFFF, p.y);
  }
}

// ---- gather SpMM, D=83(96 bf16): one wave per row, ILP-16, scalar edge loads.
// CLOSED at structural roofline: 343 MB of random 64B-line L2-miss fills at
// ~3.87 TB/s (93% of the 89 µs floor). ILP 8->16 identical (fill-path wall,
// not latency); byte-reduction variants all measured net-negative.
__global__ __launch_bounds__(256) void spmm83_g(
    const int* __restrict__ offs, const int* __restrict__ cnt,
    const int2* __restrict__ csr, const unsigned short* __restrict__ x,
    unsigned short* __restrict__ ax) {
  int wave = (int)((blockIdx.x * blockDim.x + threadIdx.x) >> 6);
  int lane = threadIdx.x & 63;
  if (wave >= NN) return;
  int s = __builtin_amdgcn_readfirstlane(offs[wave]);   // wave-uniform -> SGPR
  int n = __builtin_amdgcn_readfirstlane(cnt[wave]);
  const bool act = lane < 48;         // 48 lanes x short2 = 96 dims
  const int d2 = lane * 2;
  float a0 = 0.f, a1 = 0.f;
  int i = 0;
  for (; i + 16 <= n; i += 16) {
    int2 p[16];
#pragma unroll
    for (int u = 0; u < 16; ++u) p[u] = csr[s + i + u];
    if (act) {
      unsigned int q[16];
#pragma unroll
      for (int u = 0; u < 16; ++u)
        q[u] = *(const unsigned int*)&x[(size_t)p[u].x * XPAD + d2];
#pragma unroll
      for (int u = 0; u < 16; ++u) {
        float v = __int_as_float(p[u].y);
        a0 += v * bflo(q[u]);
        a1 += v * bfhi(q[u]);
      }
    }
  }
  for (; i + 8 <= n; i += 8) {
    int2 p[8];
#pragma unroll
    for (int u = 0; u < 8; ++u) p[u] = csr[s + i + u];
    if (act) {
      unsigned int q[8];
#pragma unroll
      for (int u = 0; u < 8; ++u)
        q[u] = *(const unsigned int*)&x[(size_t)p[u].x * XPAD + d2];
#pragma unroll
      for (int u = 0; u < 8; ++u) {
        float v = __int_as_float(p[u].y);
        a0 += v * bflo(q[u]);
        a1 += v * bfhi(q[u]);
      }
    }
  }
  for (; i < n; ++i) {
    int2 p = csr[s + i];
    if (act) {
      unsigned int q = *(const unsigned int*)&x[(size_t)p.x * XPAD + d2];
      float v = __int_as_float(p.y);
      a0 += v * bflo(q);
      a1 += v * bfhi(q);
    }
  }
  if (act) {
    unsigned int o = (unsigned int)f2bf(a0) | ((unsigned int)f2bf(a1) << 16);
    *(unsigned int*)&ax[(size_t)wave * XPAD + d2] = o;
  }
}

// ---- gather SpMM, D=25(32 bf16): 4 rows per wave (16 lanes each), ILP-8, +b2 ----
__global__ __launch_bounds__(256) void spmm25_g(
    const int* __restrict__ offs, const int* __restrict__ cnt,
    const int2* __restrict__ csr, const unsigned short* __restrict__ zb,
    const float* __restrict__ b2, float* __restrict__ out) {
  int gw = (int)((blockIdx.x * blockDim.x + threadIdx.x) >> 6);
  int lane = threadIdx.x & 63;
  int sub = lane >> 4;
  int d2 = (lane & 15) * 2;
  int r = gw * 4 + sub;
  if (r >= NN) return;
  int s = offs[r];
  int n = cnt[r];
  float a0 = 0.f, a1 = 0.f;
  int i = 0;
  for (; i + 8 <= n; i += 8) {
    int2 p[8];
#pragma unroll
    for (int u = 0; u < 8; ++u) p[u] = csr[s + i + u];
    unsigned int q[8];
#pragma unroll
    for (int u = 0; u < 8; ++u)
      q[u] = *(const unsigned int*)&zb[(size_t)p[u].x * ZPAD + d2];
#pragma unroll
    for (int u = 0; u < 8; ++u) {
      float v = __int_as_float(p[u].y);
      a0 += v * bflo(q[u]);
      a1 += v * bfhi(q[u]);
    }
  }
  for (; i < n; ++i) {
    int2 p = csr[s + i];
    unsigned int q = *(const unsigned int*)&zb[(size_t)p.x * ZPAD + d2];
    float v = __int_as_float(p.y);
    a0 += v * bflo(q);
    a1 += v * bfhi(q);
  }
  if (d2 < NCLS)     out[(size_t)r * NCLS + d2]     = a0 + b2[d2];
  if (d2 + 1 < NCLS) out[(size_t)r * NCLS + d2 + 1] = a1 + b2[d2 + 1];
}

// ---- Fused MLP via bf16 MFMA: z = relu(ax@W1+b1)@W2, z -> bf16[NN][32] ----
// Block = 128 nodes, 4 waves, hidden chunked x128 (8 chunks).
__global__ __launch_bounds__(256) void fused_mlp_mfma(
    const unsigned short* __restrict__ axg, const unsigned short* __restrict__ w1t,
    const float* __restrict__ b1, const unsigned short* __restrict__ w2t,
    unsigned short* __restrict__ zb) {
  __shared__ __align__(16) unsigned short axs[128 * 104];  // 26.6 KB
  __shared__ __align__(16) unsigned short hs[128 * 136];   // 34.8 KB (chunk 128)
  __shared__ float b1s[DHID];                              // 4 KB
  const int tid = threadIdx.x;
  const int n0 = blockIdx.x * 128;

  for (int idx = tid; idx < 128 * 12; idx += 256) {   // 12 sh8 chunks per row
    int m = idx / 12;
    int c8 = idx - m * 12;
    int node = n0 + m;
    sh8 v = {0, 0, 0, 0, 0, 0, 0, 0};
    if (node < NN) v = *(const sh8*)&axg[(size_t)node * XPAD + c8 * 8];
    *(sh8*)&axs[m * 104 + c8 * 8] = v;
  }
  for (int i = tid; i < DHID; i += 256) b1s[i] = b1[i];
  __syncthreads();

  const int lane = tid & 63;
  const int w = tid >> 6;
  const int quad = lane >> 4;   // A/B frag: k = quad*8 + j
  const int tn = lane & 15;     // A frag: m; B frag: n; C frag: col
  const int mta = w;            // GEMM2 m-tile 1
  const int mtb = w + 4;        // GEMM2 m-tile 2

  sh8 a1[8][3];
#pragma unroll
  for (int mt = 0; mt < 8; ++mt)
#pragma unroll
    for (int kc = 0; kc < 3; ++kc)
      a1[mt][kc] = *(const sh8*)&axs[(mt * 16 + tn) * 104 + kc * 32 + quad * 8];

  f4_t za0 = {0.f, 0.f, 0.f, 0.f}, za1 = {0.f, 0.f, 0.f, 0.f};
  f4_t zb0 = {0.f, 0.f, 0.f, 0.f}, zb1 = {0.f, 0.f, 0.f, 0.f};

  for (int c = 0; c < 8; ++c) {
    const int cb = c * 128;
    // GEMM1: wave w -> n-tiles w*2, w*2+1 ; all 8 m-tiles
#pragma unroll
    for (int nti = 0; nti < 2; ++nti) {
      const int nt = w * 2 + nti;
      const int ng = cb + nt * 16 + tn;
      const unsigned short* wr = &w1t[(size_t)ng * XPAD + quad * 8];
      sh8 b0 = *(const sh8*)&wr[0];
      sh8 b1f = *(const sh8*)&wr[32];
      sh8 b2f = *(const sh8*)&wr[64];
      float bias = b1s[ng];
#pragma unroll
      for (int mt = 0; mt < 8; ++mt) {
        f4_t acc = {0.f, 0.f, 0.f, 0.f};
        acc = __builtin_amdgcn_mfma_f32_16x16x32_bf16(a1[mt][0], b0, acc, 0, 0, 0);
        acc = __builtin_amdgcn_mfma_f32_16x16x32_bf16(a1[mt][1], b1f, acc, 0, 0, 0);
        acc = __builtin_amdgcn_mfma_f32_16x16x32_bf16(a1[mt][2], b2f, acc, 0, 0, 0);
#pragma unroll
        for (int r = 0; r < 4; ++r) {
          float v = relu_(acc[r] + bias);          // C: col=tn, row=quad*4+r
          hs[(mt * 16 + quad * 4 + r) * 136 + nt * 16 + tn] = f2bf(v);
        }
      }
    }
    __syncthreads();
    // GEMM2: z += h_chunk @ W2[cb..cb+127,:]; wave -> m-tiles w, w+4
#pragma unroll
    for (int kc = 0; kc < 4; ++kc) {
      sh8 bl = *(const sh8*)&w2t[(size_t)tn * DHID + cb + kc * 32 + quad * 8];
      sh8 bh = *(const sh8*)&w2t[(size_t)(16 + tn) * DHID + cb + kc * 32 + quad * 8];
      sh8 aa = *(const sh8*)&hs[(mta * 16 + tn) * 136 + kc * 32 + quad * 8];
      za0 = __builtin_amdgcn_mfma_f32_16x16x32_bf16(aa, bl, za0, 0, 0, 0);
      za1 = __builtin_amdgcn_mfma_f32_16x16x32_bf16(aa, bh, za1, 0, 0, 0);
      sh8 ab = *(const sh8*)&hs[(mtb * 16 + tn) * 136 + kc * 32 + quad * 8];
      zb0 = __builtin_amdgcn_mfma_f32_16x16x32_bf16(ab, bl, zb0, 0, 0, 0);
      zb1 = __builtin_amdgcn_mfma_f32_16x16x32_bf16(ab, bh, zb1, 0, 0, 0);
    }
    __syncthreads();
  }

#pragma unroll
  for (int r = 0; r < 4; ++r) {
    int na = n0 + mta * 16 + quad * 4 + r;
    if (na < NN) {
      zb[(size_t)na * ZPAD + tn]      = f2bf(za0[r]);
      zb[(size_t)na * ZPAD + 16 + tn] = f2bf(za1[r]);
    }
    int nb = n0 + mtb * 16 + quad * 4 + r;
    if (nb < NN) {
      zb[(size_t)nb * ZPAD + tn]      = f2bf(zb0[r]);
      zb[(size_t)nb * ZPAD + 16 + tn] = f2bf(zb1[r]);
    }
  }
}

extern "C" void kernel_launch(void* const* d_in, const int* in_sizes, int n_in,
                              void* d_out, int out_size, void* d_ws, size_t ws_size,
                              hipStream_t stream) {
  const float* feature = (const float*)d_in[0];
  const float* conv_w  = (const float*)d_in[1];
  const float* conv_b  = (const float*)d_in[2];
  const float* W1      = (const float*)d_in[3];
  const float* b1      = (const float*)d_in[4];
  const float* W2      = (const float*)d_in[5];
  const float* b2      = (const float*)d_in[6];
  const float* adj     = (const float*)d_in[7];
  const int*   erow    = (const int*)d_in[8];
  const int*   ecol    = (const int*)d_in[9];
  float* out = (float*)d_out;

  char* B = (char*)d_ws;
  size_t o = 0;
  auto alloc = [&](size_t bytes, size_t align) -> void* {
    o = (o + align - 1) & ~(align - 1);
    void* p = B + o;
    o += bytes;
    return p;
  };
  unsigned short* x    = (unsigned short*)alloc((size_t)NN * XPAD * 2, 16);
  unsigned short* ax   = (unsigned short*)alloc((size_t)NN * XPAD * 2, 16);
  unsigned short* zb   = (unsigned short*)alloc((size_t)NN * ZPAD * 2, 16);
  int*   counts  = (int*)alloc((size_t)NN * 4, 16);
  int*   offs    = (int*)alloc((size_t)NN * 4, 16);
  int*   gcur    = (int*)alloc((size_t)NBK * 16 * 4, 64);  // line-padded cursors
  unsigned short* w1t = (unsigned short*)alloc((size_t)DHID * XPAD * 2, 16);
  unsigned short* w2t = (unsigned short*)alloc((size_t)32 * DHID * 2, 16);
  int2*  tmp     = (int2*)alloc((size_t)NBK * SLAB * 8, 16);  // bucket slabs
  int2*  csr     = (int2*)alloc((size_t)NBK * SLAB * 8, 16);  // row-sorted slabs

  const int nblk_prelude = (NN + 15) / 16;   // 6250 >= all aux ranges
  // 1) prelude: conv (LDS-staged) ; transposes ; gcur+counts zero (one launch)
  prelude_k<<<nblk_prelude, 256, 0, stream>>>(
      feature, conv_w, conv_b, x, W1, w1t, W2, w2t, gcur, counts);
  // 2) build: slab partition + global row hist -> scan+scatter (tmp read once)
  partition_k<<<(EE + CHUNK - 1) / CHUNK, 256, 0, stream>>>(
      adj, erow, ecol, gcur, tmp, counts);
  fine_scatter2_k<<<NBK, 512, 0, stream>>>(gcur, counts, tmp, csr, offs);
  // 3) ax = A @ x (gather, bf16 rows, ILP-16, scalar edge loads)
  spmm83_g<<<(NN + 3) / 4, 256, 0, stream>>>(offs, counts, csr, x, ax);
  // 4) z = relu(ax @ W1 + b1) @ W2 via bf16 MFMA (128-node tiles) -> bf16 [NN][32]
  fused_mlp_mfma<<<(NN + 127) / 128, 256, 0, stream>>>(ax, w1t, b1, w2t, zb);
  // 5) out = A @ z + b2 (gather, 1 line per edge, ILP-8)
  spmm25_g<<<(NN + 15) / 16, 256, 0, stream>>>(offs, counts, csr, zb, b2, out);
}

// Round 10
// 431.753 us; speedup vs baseline: 1.2622x; 1.2622x over previous
//
#include <hip/hip_runtime.h>

#define NN   100000
#define EE   3200000
#define DIN  83
#define DHID 1024
#define NCLS 25
#define XPAD 96    // x/ax bf16 row padding (192 B = 3 cache lines)
#define ZPAD 32    // z bf16 row padding (64 B = 1 cache line)

#define NBK     391   // buckets of 256 rows (row >> 8)
#define SLAB    10240 // slab entries per bucket (mean 8192, sigma 90 -> 22 sigma)
#define CHUNK   8192  // edges per partition block

typedef __attribute__((__ext_vector_type__(8))) short sh8;
typedef __attribute__((__ext_vector_type__(4))) float f4_t;

static __device__ __forceinline__ float relu_(float v) { return v > 0.f ? v : 0.f; }

// f32 -> bf16 (RNE)
static __device__ __forceinline__ unsigned short f2bf(float f) {
  unsigned int u = __float_as_uint(f);
  unsigned int r = u + 0x7FFFu + ((u >> 16) & 1u);
  return (unsigned short)(r >> 16);
}
// packed bf16 pair -> two f32
static __device__ __forceinline__ float bflo(unsigned int q) {
  return __uint_as_float(q << 16);
}
static __device__ __forceinline__ float bfhi(unsigned int q) {
  return __uint_as_float(q & 0xFFFF0000u);
}

// K1 (merged prelude): conv1d+sum+relu -> x (LDS-staged, coalesced);
// w1t/w2t transposes ; gcur zero. Block = 16 nodes.
__global__ __launch_bounds__(256) void prelude_k(
    const float* __restrict__ feature, const float* __restrict__ conv_w,
    const float* __restrict__ conv_b, unsigned short* __restrict__ x,
    const float* __restrict__ W1, unsigned short* __restrict__ w1t,
    const float* __restrict__ W2, unsigned short* __restrict__ w2t,
    int* __restrict__ gcur) {
  const int tid = threadIdx.x;
  int t = blockIdx.x * 256 + tid;
  // --- aux ranges (low global ids) ---
  if (t < DHID * XPAD) {              // w1t[1024][96] -> [96][1024], K zero-pad
    int k = t / DHID;
    int n = t - k * DHID;
    float v = (k < DIN) ? W1[k * DHID + n] : 0.f;
    w1t[n * XPAD + k] = f2bf(v);
  }
  if (t < 32 * DHID) {                // w2t[32][1024], N zero-padded
    int k = t / 32;
    int n = t - k * 32;
    float v = (n < NCLS) ? W2[k * NCLS + n] : 0.f;
    w2t[n * DHID + k] = f2bf(v);
  }
  if (t < NBK * 16) gcur[t] = 0;
  // --- conv: 16 nodes per block ---
  const int nb0 = blockIdx.x * 16;
  if (nb0 >= NN) return;
  __shared__ float fs[16 * 84];       // 83 floats/node, pad to 84
  const size_t base = (size_t)nb0 * DIN;
  for (int i = tid; i < 16 * DIN; i += 256) {
    int nl = i / DIN;
    int dd = i - nl * DIN;
    fs[nl * 84 + dd] = feature[base + i];
  }
  __syncthreads();
  if (tid >= 192) return;             // 16 nodes x 12 groups
  int nl = tid / 12;
  int g = tid - nl * 12;
  int i0 = g * 8;
  float ws0 = conv_w[0] + conv_w[5] + conv_w[10] + conv_w[15];
  float ws1 = conv_w[1] + conv_w[6] + conv_w[11] + conv_w[16];
  float ws2 = conv_w[2] + conv_w[7] + conv_w[12] + conv_w[17];
  float ws3 = conv_w[3] + conv_w[8] + conv_w[13] + conv_w[18];
  float ws4 = conv_w[4] + conv_w[9] + conv_w[14] + conv_w[19];
  float bs  = conv_b[0] + conv_b[1] + conv_b[2] + conv_b[3];
  const float* f = &fs[nl * 84];
  float fv[12];
#pragma unroll
  for (int k = 0; k < 12; ++k) {
    int idx = i0 - 2 + k;
    fv[k] = (idx >= 0 && idx < DIN) ? f[idx] : 0.f;
  }
  sh8 vout;
#pragma unroll
  for (int j = 0; j < 8; ++j) {
    int i = i0 + j;
    unsigned short o = 0;
    if (i < DIN) {
      float acc = bs + ws0 * fv[j] + ws1 * fv[j + 1] + ws2 * fv[j + 2] +
                  ws3 * fv[j + 3] + ws4 * fv[j + 4];
      o = f2bf(relu_(acc));
    }
    vout[j] = (short)o;
  }
  *(sh8*)&x[(size_t)(nb0 + nl) * XPAD + i0] = vout;
}

// Pass 1: partition into per-bucket SLABS via direct atomic reservation.
// 512 threads (R9 showed 256-thr/391-block config at 15% occupancy,
// latency-limited). NO per-row global atomics (R9: 3.2M device atomics on a
// 400KB array = 130 µs of cross-XCD line ping-pong, WRITE_SIZE 154 MB).
__global__ __launch_bounds__(512) void partition_k(
    const float* __restrict__ vals, const int* __restrict__ row,
    const int* __restrict__ col, int* __restrict__ gcur,
    int2* __restrict__ tmp) {
  __shared__ int cnt[NBK];
  __shared__ int lcur[NBK];
  const int tid = threadIdx.x;
  const int cb = blockIdx.x * CHUNK;
  const int csize = (cb + CHUNK <= EE) ? CHUNK : (EE - cb);

  for (int b = tid; b < NBK; b += 512) cnt[b] = 0;
  __syncthreads();
  for (int i = tid; i < csize; i += 512)
    atomicAdd(&cnt[row[cb + i] >> 8], 1);
  __syncthreads();
  for (int b = tid; b < NBK; b += 512)
    lcur[b] = cnt[b] ? (b * SLAB + atomicAdd(&gcur[b * 16], cnt[b])) : 0;
  __syncthreads();
  for (int i = tid; i < csize; i += 512) {
    int r = row[cb + i];
    int pos = atomicAdd(&lcur[r >> 8], 1);
    tmp[pos] = make_int2(col[cb + i] | ((r & 255) << 17),
                         __float_as_int(vals[cb + i]));
  }
}

// Pass 2: per-bucket fine scatter + per-row offset derivation (512 threads).
// Bucket b's edges live in tmp[b*SLAB .. b*SLAB+gcur[b*16]); csr stays
// slab-addressed (offs are absolute indices, downstream is layout-agnostic).
__global__ __launch_bounds__(512) void fine_scatter2_k(
    const int* __restrict__ gcur, const int2* __restrict__ tmp,
    int2* __restrict__ csr, int* __restrict__ offs, int* __restrict__ counts) {
  __shared__ int cnt[256];
  __shared__ int sd[256];
  __shared__ int lcur[256];
  const int tid = threadIdx.x;
  const int b = blockIdx.x;
  const int r0 = b * 256;
  const int gstart = b * SLAB;
  const int nedge = gcur[b * 16];
  if (tid < 256) cnt[tid] = 0;
  __syncthreads();
  // Phase A: per-row histogram (LDS atomics, block-local)
  for (int i = tid; i < nedge; i += 512)
    atomicAdd(&cnt[((unsigned)tmp[gstart + i].x) >> 17], 1);
  __syncthreads();
  // Phase B: exclusive scan of 256 row counts (first 256 threads)
  int v = 0;
  if (tid < 256) { v = cnt[tid]; sd[tid] = v; }
  __syncthreads();
  for (int off = 1; off < 256; off <<= 1) {
    int add = (tid >= off && tid < 256) ? sd[tid - off] : 0;
    __syncthreads();
    if (tid < 256) sd[tid] += add;
    __syncthreads();
  }
  if (tid < 256) {
    int excl = gstart + sd[tid] - v;
    int r = r0 + tid;
    if (r < NN) {
      offs[r] = excl;
      counts[r] = v;
    }
    lcur[tid] = excl;
  }
  __syncthreads();
  // Phase C: scatter within the bucket's slab window (L2-local)
  for (int i = tid; i < nedge; i += 512) {
    int2 p = tmp[gstart + i];
    int rl = ((unsigned)p.x) >> 17;
    int pos = atomicAdd(&lcur[rl], 1);
    csr[pos] = make_int2(p.x & 0x1FFFF, p.y);
  }
}

// ---- gather SpMM, D=83(96 bf16): one wave per row, ILP-16, scalar edge loads.
// CLOSED at structural roofline: 343 MB of random 64B-line L2-miss fills at
// ~3.87 TB/s (93% of the 89 µs floor). ILP 8->16 identical (fill-path wall,
// not latency); byte-reduction variants all measured net-negative.
__global__ __launch_bounds__(256) void spmm83_g(
    const int* __restrict__ offs, const int* __restrict__ cnt,
    const int2* __restrict__ csr, const unsigned short* __restrict__ x,
    unsigned short* __restrict__ ax) {
  int wave = (int)((blockIdx.x * blockDim.x + threadIdx.x) >> 6);
  int lane = threadIdx.x & 63;
  if (wave >= NN) return;
  int s = __builtin_amdgcn_readfirstlane(offs[wave]);   // wave-uniform -> SGPR
  int n = __builtin_amdgcn_readfirstlane(cnt[wave]);
  const bool act = lane < 48;         // 48 lanes x short2 = 96 dims
  const int d2 = lane * 2;
  float a0 = 0.f, a1 = 0.f;
  int i = 0;
  for (; i + 16 <= n; i += 16) {
    int2 p[16];
#pragma unroll
    for (int u = 0; u < 16; ++u) p[u] = csr[s + i + u];
    if (act) {
      unsigned int q[16];
#pragma unroll
      for (int u = 0; u < 16; ++u)
        q[u] = *(const unsigned int*)&x[(size_t)p[u].x * XPAD + d2];
#pragma unroll
      for (int u = 0; u < 16; ++u) {
        float v = __int_as_float(p[u].y);
        a0 += v * bflo(q[u]);
        a1 += v * bfhi(q[u]);
      }
    }
  }
  for (; i + 8 <= n; i += 8) {
    int2 p[8];
#pragma unroll
    for (int u = 0; u < 8; ++u) p[u] = csr[s + i + u];
    if (act) {
      unsigned int q[8];
#pragma unroll
      for (int u = 0; u < 8; ++u)
        q[u] = *(const unsigned int*)&x[(size_t)p[u].x * XPAD + d2];
#pragma unroll
      for (int u = 0; u < 8; ++u) {
        float v = __int_as_float(p[u].y);
        a0 += v * bflo(q[u]);
        a1 += v * bfhi(q[u]);
      }
    }
  }
  for (; i < n; ++i) {
    int2 p = csr[s + i];
    if (act) {
      unsigned int q = *(const unsigned int*)&x[(size_t)p.x * XPAD + d2];
      float v = __int_as_float(p.y);
      a0 += v * bflo(q);
      a1 += v * bfhi(q);
    }
  }
  if (act) {
    unsigned int o = (unsigned int)f2bf(a0) | ((unsigned int)f2bf(a1) << 16);
    *(unsigned int*)&ax[(size_t)wave * XPAD + d2] = o;
  }
}

// ---- gather SpMM, D=25(32 bf16): 4 rows per wave (16 lanes each), ILP-8, +b2 ----
__global__ __launch_bounds__(256) void spmm25_g(
    const int* __restrict__ offs, const int* __restrict__ cnt,
    const int2* __restrict__ csr, const unsigned short* __restrict__ zb,
    const float* __restrict__ b2, float* __restrict__ out) {
  int gw = (int)((blockIdx.x * blockDim.x + threadIdx.x) >> 6);
  int lane = threadIdx.x & 63;
  int sub = lane >> 4;
  int d2 = (lane & 15) * 2;
  int r = gw * 4 + sub;
  if (r >= NN) return;
  int s = offs[r];
  int n = cnt[r];
  float a0 = 0.f, a1 = 0.f;
  int i = 0;
  for (; i + 8 <= n; i += 8) {
    int2 p[8];
#pragma unroll
    for (int u = 0; u < 8; ++u) p[u] = csr[s + i + u];
    unsigned int q[8];
#pragma unroll
    for (int u = 0; u < 8; ++u)
      q[u] = *(const unsigned int*)&zb[(size_t)p[u].x * ZPAD + d2];
#pragma unroll
    for (int u = 0; u < 8; ++u) {
      float v = __int_as_float(p[u].y);
      a0 += v * bflo(q[u]);
      a1 += v * bfhi(q[u]);
    }
  }
  for (; i < n; ++i) {
    int2 p = csr[s + i];
    unsigned int q = *(const unsigned int*)&zb[(size_t)p.x * ZPAD + d2];
    float v = __int_as_float(p.y);
    a0 += v * bflo(q);
    a1 += v * bfhi(q);
  }
  if (d2 < NCLS)     out[(size_t)r * NCLS + d2]     = a0 + b2[d2];
  if (d2 + 1 < NCLS) out[(size_t)r * NCLS + d2 + 1] = a1 + b2[d2 + 1];
}

// ---- Fused MLP via bf16 MFMA: z = relu(ax@W1+b1)@W2, z -> bf16[NN][32] ----
// Block = 128 nodes, 4 waves, hidden chunked x128 (8 chunks).
__global__ __launch_bounds__(256) void fused_mlp_mfma(
    const unsigned short* __restrict__ axg, const unsigned short* __restrict__ w1t,
    const float* __restrict__ b1, const unsigned short* __restrict__ w2t,
    unsigned short* __restrict__ zb) {
  __shared__ __align__(16) unsigned short axs[128 * 104];  // 26.6 KB
  __shared__ __align__(16) unsigned short hs[128 * 136];   // 34.8 KB (chunk 128)
  __shared__ float b1s[DHID];                              // 4 KB
  const int tid = threadIdx.x;
  const int n0 = blockIdx.x * 128;

  for (int idx = tid; idx < 128 * 12; idx += 256) {   // 12 sh8 chunks per row
    int m = idx / 12;
    int c8 = idx - m * 12;
    int node = n0 + m;
    sh8 v = {0, 0, 0, 0, 0, 0, 0, 0};
    if (node < NN) v = *(const sh8*)&axg[(size_t)node * XPAD + c8 * 8];
    *(sh8*)&axs[m * 104 + c8 * 8] = v;
  }
  for (int i = tid; i < DHID; i += 256) b1s[i] = b1[i];
  __syncthreads();

  const int lane = tid & 63;
  const int w = tid >> 6;
  const int quad = lane >> 4;   // A/B frag: k = quad*8 + j
  const int tn = lane & 15;     // A frag: m; B frag: n; C frag: col
  const int mta = w;            // GEMM2 m-tile 1
  const int mtb = w + 4;        // GEMM2 m-tile 2

  sh8 a1[8][3];
#pragma unroll
  for (int mt = 0; mt < 8; ++mt)
#pragma unroll
    for (int kc = 0; kc < 3; ++kc)
      a1[mt][kc] = *(const sh8*)&axs[(mt * 16 + tn) * 104 + kc * 32 + quad * 8];

  f4_t za0 = {0.f, 0.f, 0.f, 0.f}, za1 = {0.f, 0.f, 0.f, 0.f};
  f4_t zb0 = {0.f, 0.f, 0.f, 0.f}, zb1 = {0.f, 0.f, 0.f, 0.f};

  for (int c = 0; c < 8; ++c) {
    const int cb = c * 128;
    // GEMM1: wave w -> n-tiles w*2, w*2+1 ; all 8 m-tiles
#pragma unroll
    for (int nti = 0; nti < 2; ++nti) {
      const int nt = w * 2 + nti;
      const int ng = cb + nt * 16 + tn;
      const unsigned short* wr = &w1t[(size_t)ng * XPAD + quad * 8];
      sh8 b0 = *(const sh8*)&wr[0];
      sh8 b1f = *(const sh8*)&wr[32];
      sh8 b2f = *(const sh8*)&wr[64];
      float bias = b1s[ng];
#pragma unroll
      for (int mt = 0; mt < 8; ++mt) {
        f4_t acc = {0.f, 0.f, 0.f, 0.f};
        acc = __builtin_amdgcn_mfma_f32_16x16x32_bf16(a1[mt][0], b0, acc, 0, 0, 0);
        acc = __builtin_amdgcn_mfma_f32_16x16x32_bf16(a1[mt][1], b1f, acc, 0, 0, 0);
        acc = __builtin_amdgcn_mfma_f32_16x16x32_bf16(a1[mt][2], b2f, acc, 0, 0, 0);
#pragma unroll
        for (int r = 0; r < 4; ++r) {
          float v = relu_(acc[r] + bias);          // C: col=tn, row=quad*4+r
          hs[(mt * 16 + quad * 4 + r) * 136 + nt * 16 + tn] = f2bf(v);
        }
      }
    }
    __syncthreads();
    // GEMM2: z += h_chunk @ W2[cb..cb+127,:]; wave -> m-tiles w, w+4
#pragma unroll
    for (int kc = 0; kc < 4; ++kc) {
      sh8 bl = *(const sh8*)&w2t[(size_t)tn * DHID + cb + kc * 32 + quad * 8];
      sh8 bh = *(const sh8*)&w2t[(size_t)(16 + tn) * DHID + cb + kc * 32 + quad * 8];
      sh8 aa = *(const sh8*)&hs[(mta * 16 + tn) * 136 + kc * 32 + quad * 8];
      za0 = __builtin_amdgcn_mfma_f32_16x16x32_bf16(aa, bl, za0, 0, 0, 0);
      za1 = __builtin_amdgcn_mfma_f32_16x16x32_bf16(aa, bh, za1, 0, 0, 0);
      sh8 ab = *(const sh8*)&hs[(mtb * 16 + tn) * 136 + kc * 32 + quad * 8];
      zb0 = __builtin_amdgcn_mfma_f32_16x16x32_bf16(ab, bl, zb0, 0, 0, 0);
      zb1 = __builtin_amdgcn_mfma_f32_16x16x32_bf16(ab, bh, zb1, 0, 0, 0);
    }
    __syncthreads();
  }

#pragma unroll
  for (int r = 0; r < 4; ++r) {
    int na = n0 + mta * 16 + quad * 4 + r;
    if (na < NN) {
      zb[(size_t)na * ZPAD + tn]      = f2bf(za0[r]);
      zb[(size_t)na * ZPAD + 16 + tn] = f2bf(za1[r]);
    }
    int nb = n0 + mtb * 16 + quad * 4 + r;
    if (nb < NN) {
      zb[(size_t)nb * ZPAD + tn]      = f2bf(zb0[r]);
      zb[(size_t)nb * ZPAD + 16 + tn] = f2bf(zb1[r]);
    }
  }
}

extern "C" void kernel_launch(void* const* d_in, const int* in_sizes, int n_in,
                              void* d_out, int out_size, void* d_ws, size_t ws_size,
                              hipStream_t stream) {
  const float* feature = (const float*)d_in[0];
  const float* conv_w  = (const float*)d_in[1];
  const float* conv_b  = (const float*)d_in[2];
  const float* W1      = (const float*)d_in[3];
  const float* b1      = (const float*)d_in[4];
  const float* W2      = (const float*)d_in[5];
  const float* b2      = (const float*)d_in[6];
  const float* adj     = (const float*)d_in[7];
  const int*   erow    = (const int*)d_in[8];
  const int*   ecol    = (const int*)d_in[9];
  float* out = (float*)d_out;

  char* B = (char*)d_ws;
  size_t o = 0;
  auto alloc = [&](size_t bytes, size_t align) -> void* {
    o = (o + align - 1) & ~(align - 1);
    void* p = B + o;
    o += bytes;
    return p;
  };
  unsigned short* x    = (unsigned short*)alloc((size_t)NN * XPAD * 2, 16);
  unsigned short* ax   = (unsigned short*)alloc((size_t)NN * XPAD * 2, 16);
  unsigned short* zb   = (unsigned short*)alloc((size_t)NN * ZPAD * 2, 16);
  int*   counts  = (int*)alloc((size_t)NN * 4, 16);
  int*   offs    = (int*)alloc((size_t)NN * 4, 16);
  int*   gcur    = (int*)alloc((size_t)NBK * 16 * 4, 64);  // line-padded cursors
  unsigned short* w1t = (unsigned short*)alloc((size_t)DHID * XPAD * 2, 16);
  unsigned short* w2t = (unsigned short*)alloc((size_t)32 * DHID * 2, 16);
  int2*  tmp     = (int2*)alloc((size_t)NBK * SLAB * 8, 16);  // bucket slabs
  int2*  csr     = (int2*)alloc((size_t)NBK * SLAB * 8, 16);  // row-sorted slabs

  const int nblk_prelude = (NN + 15) / 16;   // 6250 >= all aux ranges
  // 1) prelude: conv (LDS-staged) ; transposes ; gcur zero (one launch)
  prelude_k<<<nblk_prelude, 256, 0, stream>>>(
      feature, conv_w, conv_b, x, W1, w1t, W2, w2t, gcur);
  // 2) build: slab partition (512 thr) -> fine scatter (block-local hists only)
  partition_k<<<(EE + CHUNK - 1) / CHUNK, 512, 0, stream>>>(
      adj, erow, ecol, gcur, tmp);
  fine_scatter2_k<<<NBK, 512, 0, stream>>>(gcur, tmp, csr, offs, counts);
  // 3) ax = A @ x (gather, bf16 rows, ILP-16, scalar edge loads)
  spmm83_g<<<(NN + 3) / 4, 256, 0, stream>>>(offs, counts, csr, x, ax);
  // 4) z = relu(ax @ W1 + b1) @ W2 via bf16 MFMA (128-node tiles) -> bf16 [NN][32]
  fused_mlp_mfma<<<(NN + 127) / 128, 256, 0, stream>>>(ax, w1t, b1, w2t, zb);
  // 5) out = A @ z + b2 (gather, 1 line per edge, ILP-8)
  spmm25_g<<<(NN + 15) / 16, 256, 0, stream>>>(offs, counts, csr, zb, b2, out);
}

// Round 11
// 425.242 us; speedup vs baseline: 1.2815x; 1.0153x over previous
//
#include <hip/hip_runtime.h>

#define NN   100000
#define EE   3200000
#define DIN  83
#define DHID 1024
#define NCLS 25
#define XPAD 96    // x/ax bf16 row padding (192 B = 3 cache lines)
#define ZPAD 32    // z bf16 row padding (64 B = 1 cache line)

#define NBK     391   // buckets of 256 rows (row >> 8)
#define SLAB    10240 // slab entries per bucket (mean 8192, sigma 90 -> 22 sigma)
#define CHUNK   8192  // edges per partition block
#define NPART   391   // partition blocks = (EE+CHUNK-1)/CHUNK
#define NCONVB  3125  // conv blocks (32 nodes each)
#define EBUF    9216  // fine_scatter LDS edge buffer (mean + 11 sigma)

typedef __attribute__((__ext_vector_type__(8))) short sh8;
typedef __attribute__((__ext_vector_type__(4))) float f4_t;

static __device__ __forceinline__ float relu_(float v) { return v > 0.f ? v : 0.f; }

// f32 -> bf16 (RNE)
static __device__ __forceinline__ unsigned short f2bf(float f) {
  unsigned int u = __float_as_uint(f);
  unsigned int r = u + 0x7FFFu + ((u >> 16) & 1u);
  return (unsigned short)(r >> 16);
}
// packed bf16 pair -> two f32
static __device__ __forceinline__ float bflo(unsigned int q) {
  return __uint_as_float(q << 16);
}
static __device__ __forceinline__ float bfhi(unsigned int q) {
  return __uint_as_float(q & 0xFFFF0000u);
}

// K1 (merged build): blocks [0,NPART) = slab partition (latency-bound,
// low-occupancy); blocks [NPART, NPART+NCONVB) = conv+transposes (BW-bound).
// Independent roles overlap on the CUs; gcur is pre-zeroed by hipMemsetAsync.
__global__ __launch_bounds__(512) void build_k(
    const float* __restrict__ vals, const int* __restrict__ row,
    const int* __restrict__ col, int* __restrict__ gcur,
    int2* __restrict__ tmp,
    const float* __restrict__ feature, const float* __restrict__ conv_w,
    const float* __restrict__ conv_b, unsigned short* __restrict__ x,
    const float* __restrict__ W1, unsigned short* __restrict__ w1t,
    const float* __restrict__ W2, unsigned short* __restrict__ w2t) {
  __shared__ __align__(16) int shm[32 * 84];   // 10.75 KB, aliased per role
  const int tid = threadIdx.x;

  if (blockIdx.x < NPART) {
    // ---- partition role (verbatim R10 structure, 512 threads) ----
    int* cnt  = shm;          // [NBK]
    int* lcur = shm + NBK;    // [NBK]
    const int cb = blockIdx.x * CHUNK;
    const int csize = (cb + CHUNK <= EE) ? CHUNK : (EE - cb);
    for (int b = tid; b < NBK; b += 512) cnt[b] = 0;
    __syncthreads();
    for (int i = tid; i < csize; i += 512)
      atomicAdd(&cnt[row[cb + i] >> 8], 1);
    __syncthreads();
    for (int b = tid; b < NBK; b += 512)
      lcur[b] = cnt[b] ? (b * SLAB + atomicAdd(&gcur[b * 16], cnt[b])) : 0;
    __syncthreads();
    for (int i = tid; i < csize; i += 512) {
      int r = row[cb + i];
      int pos = atomicAdd(&lcur[r >> 8], 1);
      tmp[pos] = make_int2(col[cb + i] | ((r & 255) << 17),
                           __float_as_int(vals[cb + i]));
    }
    return;
  }

  // ---- conv + weight-transpose role ----
  const int cbk = blockIdx.x - NPART;     // 0 .. NCONVB-1
  int t = cbk * 512 + tid;
  if (t < DHID * XPAD) {              // w1t[1024][96] -> [96][1024], K zero-pad
    int k = t / DHID;
    int n = t - k * DHID;
    float v = (k < DIN) ? W1[k * DHID + n] : 0.f;
    w1t[n * XPAD + k] = f2bf(v);
  }
  if (t < 32 * DHID) {                // w2t[32][1024], N zero-padded
    int k = t / 32;
    int n = t - k * 32;
    float v = (n < NCLS) ? W2[k * NCLS + n] : 0.f;
    w2t[n * DHID + k] = f2bf(v);
  }
  const int nb0 = cbk * 32;           // 32 nodes per block; 3125*32 = NN exactly
  if (nb0 >= NN) return;
  float* fs = (float*)shm;            // [32][84]
  const size_t base = (size_t)nb0 * DIN;
  for (int i = tid; i < 32 * DIN; i += 512) {
    int nl = i / DIN;
    int dd = i - nl * DIN;
    fs[nl * 84 + dd] = feature[base + i];
  }
  __syncthreads();
  if (tid >= 384) return;             // 32 nodes x 12 groups
  int nl = tid / 12;
  int g = tid - nl * 12;
  int i0 = g * 8;
  float ws0 = conv_w[0] + conv_w[5] + conv_w[10] + conv_w[15];
  float ws1 = conv_w[1] + conv_w[6] + conv_w[11] + conv_w[16];
  float ws2 = conv_w[2] + conv_w[7] + conv_w[12] + conv_w[17];
  float ws3 = conv_w[3] + conv_w[8] + conv_w[13] + conv_w[18];
  float ws4 = conv_w[4] + conv_w[9] + conv_w[14] + conv_w[19];
  float bs  = conv_b[0] + conv_b[1] + conv_b[2] + conv_b[3];
  const float* f = &fs[nl * 84];
  float fv[12];
#pragma unroll
  for (int k = 0; k < 12; ++k) {
    int idx = i0 - 2 + k;
    fv[k] = (idx >= 0 && idx < DIN) ? f[idx] : 0.f;
  }
  sh8 vout;
#pragma unroll
  for (int j = 0; j < 8; ++j) {
    int i = i0 + j;
    unsigned short o = 0;
    if (i < DIN) {
      float acc = bs + ws0 * fv[j] + ws1 * fv[j + 1] + ws2 * fv[j + 2] +
                  ws3 * fv[j + 3] + ws4 * fv[j + 4];
      o = f2bf(relu_(acc));
    }
    vout[j] = (short)o;
  }
  *(sh8*)&x[(size_t)(nb0 + nl) * XPAD + i0] = vout;
}

// Pass 2: per-bucket fine scatter, LDS-staged (bucket window read from global
// ONCE). 75 KB LDS -> 2 blocks/CU. Uniform fallback to global reads if a
// bucket ever exceeds EBUF (11 sigma; not expected for this input).
__global__ __launch_bounds__(512) void fine_scatter2_k(
    const int* __restrict__ gcur, const int2* __restrict__ tmp,
    int2* __restrict__ csr, int* __restrict__ offs, int* __restrict__ counts) {
  __shared__ int2 ebuf[EBUF];         // 72 KB
  __shared__ int cnt[256];
  __shared__ int sd[256];
  __shared__ int lcur[256];
  const int tid = threadIdx.x;
  const int b = blockIdx.x;
  const int r0 = b * 256;
  const int gstart = b * SLAB;
  const int nedge = gcur[b * 16];
  const bool fit = (nedge <= EBUF);   // block-uniform
  if (tid < 256) cnt[tid] = 0;
  if (fit)
    for (int i = tid; i < nedge; i += 512) ebuf[i] = tmp[gstart + i];
  __syncthreads();
  // Phase A: per-row histogram (LDS atomics, block-local)
  for (int i = tid; i < nedge; i += 512) {
    int px = fit ? ebuf[i].x : tmp[gstart + i].x;
    atomicAdd(&cnt[((unsigned)px) >> 17], 1);
  }
  __syncthreads();
  // Phase B: exclusive scan of 256 row counts (first 256 threads)
  int v = 0;
  if (tid < 256) { v = cnt[tid]; sd[tid] = v; }
  __syncthreads();
  for (int off = 1; off < 256; off <<= 1) {
    int add = (tid >= off && tid < 256) ? sd[tid - off] : 0;
    __syncthreads();
    if (tid < 256) sd[tid] += add;
    __syncthreads();
  }
  if (tid < 256) {
    int excl = gstart + sd[tid] - v;
    int r = r0 + tid;
    if (r < NN) {
      offs[r] = excl;
      counts[r] = v;
    }
    lcur[tid] = excl;
  }
  __syncthreads();
  // Phase C: scatter from LDS into the bucket's slab window (L2-local)
  for (int i = tid; i < nedge; i += 512) {
    int2 p = fit ? ebuf[i] : tmp[gstart + i];
    int rl = ((unsigned)p.x) >> 17;
    int pos = atomicAdd(&lcur[rl], 1);
    csr[pos] = make_int2(p.x & 0x1FFFF, p.y);
  }
}

// ---- gather SpMM, D=83(96 bf16): one wave per row, ILP-16, scalar edge loads.
// CLOSED at structural roofline: 343 MB of random 64B-line L2-miss fills at
// ~3.87 TB/s (93% of the 89 µs floor). ILP 8->16 identical (fill-path wall,
// not latency); byte-reduction variants all measured net-negative.
__global__ __launch_bounds__(256) void spmm83_g(
    const int* __restrict__ offs, const int* __restrict__ cnt,
    const int2* __restrict__ csr, const unsigned short* __restrict__ x,
    unsigned short* __restrict__ ax) {
  int wave = (int)((blockIdx.x * blockDim.x + threadIdx.x) >> 6);
  int lane = threadIdx.x & 63;
  if (wave >= NN) return;
  int s = __builtin_amdgcn_readfirstlane(offs[wave]);   // wave-uniform -> SGPR
  int n = __builtin_amdgcn_readfirstlane(cnt[wave]);
  const bool act = lane < 48;         // 48 lanes x short2 = 96 dims
  const int d2 = lane * 2;
  float a0 = 0.f, a1 = 0.f;
  int i = 0;
  for (; i + 16 <= n; i += 16) {
    int2 p[16];
#pragma unroll
    for (int u = 0; u < 16; ++u) p[u] = csr[s + i + u];
    if (act) {
      unsigned int q[16];
#pragma unroll
      for (int u = 0; u < 16; ++u)
        q[u] = *(const unsigned int*)&x[(size_t)p[u].x * XPAD + d2];
#pragma unroll
      for (int u = 0; u < 16; ++u) {
        float v = __int_as_float(p[u].y);
        a0 += v * bflo(q[u]);
        a1 += v * bfhi(q[u]);
      }
    }
  }
  for (; i + 8 <= n; i += 8) {
    int2 p[8];
#pragma unroll
    for (int u = 0; u < 8; ++u) p[u] = csr[s + i + u];
    if (act) {
      unsigned int q[8];
#pragma unroll
      for (int u = 0; u < 8; ++u)
        q[u] = *(const unsigned int*)&x[(size_t)p[u].x * XPAD + d2];
#pragma unroll
      for (int u = 0; u < 8; ++u) {
        float v = __int_as_float(p[u].y);
        a0 += v * bflo(q[u]);
        a1 += v * bfhi(q[u]);
      }
    }
  }
  for (; i < n; ++i) {
    int2 p = csr[s + i];
    if (act) {
      unsigned int q = *(const unsigned int*)&x[(size_t)p.x * XPAD + d2];
      float v = __int_as_float(p.y);
      a0 += v * bflo(q);
      a1 += v * bfhi(q);
    }
  }
  if (act) {
    unsigned int o = (unsigned int)f2bf(a0) | ((unsigned int)f2bf(a1) << 16);
    *(unsigned int*)&ax[(size_t)wave * XPAD + d2] = o;
  }
}

// ---- gather SpMM, D=25(32 bf16): 4 rows per wave (16 lanes each), ILP-8, +b2 ----
__global__ __launch_bounds__(256) void spmm25_g(
    const int* __restrict__ offs, const int* __restrict__ cnt,
    const int2* __restrict__ csr, const unsigned short* __restrict__ zb,
    const float* __restrict__ b2, float* __restrict__ out) {
  int gw = (int)((blockIdx.x * blockDim.x + threadIdx.x) >> 6);
  int lane = threadIdx.x & 63;
  int sub = lane >> 4;
  int d2 = (lane & 15) * 2;
  int r = gw * 4 + sub;
  if (r >= NN) return;
  int s = offs[r];
  int n = cnt[r];
  float a0 = 0.f, a1 = 0.f;
  int i = 0;
  for (; i + 8 <= n; i += 8) {
    int2 p[8];
#pragma unroll
    for (int u = 0; u < 8; ++u) p[u] = csr[s + i + u];
    unsigned int q[8];
#pragma unroll
    for (int u = 0; u < 8; ++u)
      q[u] = *(const unsigned int*)&zb[(size_t)p[u].x * ZPAD + d2];
#pragma unroll
    for (int u = 0; u < 8; ++u) {
      float v = __int_as_float(p[u].y);
      a0 += v * bflo(q[u]);
      a1 += v * bfhi(q[u]);
    }
  }
  for (; i < n; ++i) {
    int2 p = csr[s + i];
    unsigned int q = *(const unsigned int*)&zb[(size_t)p.x * ZPAD + d2];
    float v = __int_as_float(p.y);
    a0 += v * bflo(q);
    a1 += v * bfhi(q);
  }
  if (d2 < NCLS)     out[(size_t)r * NCLS + d2]     = a0 + b2[d2];
  if (d2 + 1 < NCLS) out[(size_t)r * NCLS + d2 + 1] = a1 + b2[d2 + 1];
}

// ---- Fused MLP via bf16 MFMA: z = relu(ax@W1+b1)@W2, z -> bf16[NN][32] ----
// Block = 128 nodes, 4 waves, hidden chunked x128 (8 chunks).
__global__ __launch_bounds__(256) void fused_mlp_mfma(
    const unsigned short* __restrict__ axg, const unsigned short* __restrict__ w1t,
    const float* __restrict__ b1, const unsigned short* __restrict__ w2t,
    unsigned short* __restrict__ zb) {
  __shared__ __align__(16) unsigned short axs[128 * 104];  // 26.6 KB
  __shared__ __align__(16) unsigned short hs[128 * 136];   // 34.8 KB (chunk 128)
  __shared__ float b1s[DHID];                              // 4 KB
  const int tid = threadIdx.x;
  const int n0 = blockIdx.x * 128;

  for (int idx = tid; idx < 128 * 12; idx += 256) {   // 12 sh8 chunks per row
    int m = idx / 12;
    int c8 = idx - m * 12;
    int node = n0 + m;
    sh8 v = {0, 0, 0, 0, 0, 0, 0, 0};
    if (node < NN) v = *(const sh8*)&axg[(size_t)node * XPAD + c8 * 8];
    *(sh8*)&axs[m * 104 + c8 * 8] = v;
  }
  for (int i = tid; i < DHID; i += 256) b1s[i] = b1[i];
  __syncthreads();

  const int lane = tid & 63;
  const int w = tid >> 6;
  const int quad = lane >> 4;   // A/B frag: k = quad*8 + j
  const int tn = lane & 15;     // A frag: m; B frag: n; C frag: col
  const int mta = w;            // GEMM2 m-tile 1
  const int mtb = w + 4;        // GEMM2 m-tile 2

  sh8 a1[8][3];
#pragma unroll
  for (int mt = 0; mt < 8; ++mt)
#pragma unroll
    for (int kc = 0; kc < 3; ++kc)
      a1[mt][kc] = *(const sh8*)&axs[(mt * 16 + tn) * 104 + kc * 32 + quad * 8];

  f4_t za0 = {0.f, 0.f, 0.f, 0.f}, za1 = {0.f, 0.f, 0.f, 0.f};
  f4_t zb0 = {0.f, 0.f, 0.f, 0.f}, zb1 = {0.f, 0.f, 0.f, 0.f};

  for (int c = 0; c < 8; ++c) {
    const int cb = c * 128;
    // GEMM1: wave w -> n-tiles w*2, w*2+1 ; all 8 m-tiles
#pragma unroll
    for (int nti = 0; nti < 2; ++nti) {
      const int nt = w * 2 + nti;
      const int ng = cb + nt * 16 + tn;
      const unsigned short* wr = &w1t[(size_t)ng * XPAD + quad * 8];
      sh8 b0 = *(const sh8*)&wr[0];
      sh8 b1f = *(const sh8*)&wr[32];
      sh8 b2f = *(const sh8*)&wr[64];
      float bias = b1s[ng];
#pragma unroll
      for (int mt = 0; mt < 8; ++mt) {
        f4_t acc = {0.f, 0.f, 0.f, 0.f};
        acc = __builtin_amdgcn_mfma_f32_16x16x32_bf16(a1[mt][0], b0, acc, 0, 0, 0);
        acc = __builtin_amdgcn_mfma_f32_16x16x32_bf16(a1[mt][1], b1f, acc, 0, 0, 0);
        acc = __builtin_amdgcn_mfma_f32_16x16x32_bf16(a1[mt][2], b2f, acc, 0, 0, 0);
#pragma unroll
        for (int r = 0; r < 4; ++r) {
          float v = relu_(acc[r] + bias);          // C: col=tn, row=quad*4+r
          hs[(mt * 16 + quad * 4 + r) * 136 + nt * 16 + tn] = f2bf(v);
        }
      }
    }
    __syncthreads();
    // GEMM2: z += h_chunk @ W2[cb..cb+127,:]; wave -> m-tiles w, w+4
#pragma unroll
    for (int kc = 0; kc < 4; ++kc) {
      sh8 bl = *(const sh8*)&w2t[(size_t)tn * DHID + cb + kc * 32 + quad * 8];
      sh8 bh = *(const sh8*)&w2t[(size_t)(16 + tn) * DHID + cb + kc * 32 + quad * 8];
      sh8 aa = *(const sh8*)&hs[(mta * 16 + tn) * 136 + kc * 32 + quad * 8];
      za0 = __builtin_amdgcn_mfma_f32_16x16x32_bf16(aa, bl, za0, 0, 0, 0);
      za1 = __builtin_amdgcn_mfma_f32_16x16x32_bf16(aa, bh, za1, 0, 0, 0);
      sh8 ab = *(const sh8*)&hs[(mtb * 16 + tn) * 136 + kc * 32 + quad * 8];
      zb0 = __builtin_amdgcn_mfma_f32_16x16x32_bf16(ab, bl, zb0, 0, 0, 0);
      zb1 = __builtin_amdgcn_mfma_f32_16x16x32_bf16(ab, bh, zb1, 0, 0, 0);
    }
    __syncthreads();
  }

#pragma unroll
  for (int r = 0; r < 4; ++r) {
    int na = n0 + mta * 16 + quad * 4 + r;
    if (na < NN) {
      zb[(size_t)na * ZPAD + tn]      = f2bf(za0[r]);
      zb[(size_t)na * ZPAD + 16 + tn] = f2bf(za1[r]);
    }
    int nb = n0 + mtb * 16 + quad * 4 + r;
    if (nb < NN) {
      zb[(size_t)nb * ZPAD + tn]      = f2bf(zb0[r]);
      zb[(size_t)nb * ZPAD + 16 + tn] = f2bf(zb1[r]);
    }
  }
}

extern "C" void kernel_launch(void* const* d_in, const int* in_sizes, int n_in,
                              void* d_out, int out_size, void* d_ws, size_t ws_size,
                              hipStream_t stream) {
  const float* feature = (const float*)d_in[0];
  const float* conv_w  = (const float*)d_in[1];
  const float* conv_b  = (const float*)d_in[2];
  const float* W1      = (const float*)d_in[3];
  const float* b1      = (const float*)d_in[4];
  const float* W2      = (const float*)d_in[5];
  const float* b2      = (const float*)d_in[6];
  const float* adj     = (const float*)d_in[7];
  const int*   erow    = (const int*)d_in[8];
  const int*   ecol    = (const int*)d_in[9];
  float* out = (float*)d_out;

  char* B = (char*)d_ws;
  size_t o = 0;
  auto alloc = [&](size_t bytes, size_t align) -> void* {
    o = (o + align - 1) & ~(align - 1);
    void* p = B + o;
    o += bytes;
    return p;
  };
  unsigned short* x    = (unsigned short*)alloc((size_t)NN * XPAD * 2, 16);
  unsigned short* ax   = (unsigned short*)alloc((size_t)NN * XPAD * 2, 16);
  unsigned short* zb   = (unsigned short*)alloc((size_t)NN * ZPAD * 2, 16);
  int*   counts  = (int*)alloc((size_t)NN * 4, 16);
  int*   offs    = (int*)alloc((size_t)NN * 4, 16);
  int*   gcur    = (int*)alloc((size_t)NBK * 16 * 4, 64);  // line-padded cursors
  unsigned short* w1t = (unsigned short*)alloc((size_t)DHID * XPAD * 2, 16);
  unsigned short* w2t = (unsigned short*)alloc((size_t)32 * DHID * 2, 16);
  int2*  tmp     = (int2*)alloc((size_t)NBK * SLAB * 8, 16);  // bucket slabs
  int2*  csr     = (int2*)alloc((size_t)NBK * SLAB * 8, 16);  // row-sorted slabs

  // 0) zero slab cursors (capturable stream-ordered memset)
  hipMemsetAsync(gcur, 0, (size_t)NBK * 16 * 4, stream);
  // 1) merged build: partition blocks [0,391) + conv/transpose blocks [391,3516)
  build_k<<<NPART + NCONVB, 512, 0, stream>>>(
      adj, erow, ecol, gcur, tmp,
      feature, conv_w, conv_b, x, W1, w1t, W2, w2t);
  // 2) fine scatter (LDS-staged bucket window, read tmp once)
  fine_scatter2_k<<<NBK, 512, 0, stream>>>(gcur, tmp, csr, offs, counts);
  // 3) ax = A @ x (gather, bf16 rows, ILP-16, scalar edge loads)
  spmm83_g<<<(NN + 3) / 4, 256, 0, stream>>>(offs, counts, csr, x, ax);
  // 4) z = relu(ax @ W1 + b1) @ W2 via bf16 MFMA (128-node tiles) -> bf16 [NN][32]
  fused_mlp_mfma<<<(NN + 127) / 128, 256, 0, stream>>>(ax, w1t, b1, w2t, zb);
  // 5) out = A @ z + b2 (gather, 1 line per edge, ILP-8)
  spmm25_g<<<(NN + 15) / 16, 256, 0, stream>>>(offs, counts, csr, zb, b2, out);
}